// Round 11
// baseline (189.932 us; speedup 1.0000x reference)
//
#include <hip/hip_runtime.h>

// VectorQuantizer: x [2,8,48,48,48] f32, embed [512,8] f32
// d_out: loss (1) | out (1769472) | encodings (221184*512 = 113246208)
// R11: STRICT SERIAL SPLIT of measured-good phases:
//   K1 argmin  (R5's LDS/4pt structure, no enc stores)      ~30 us
//   K2 fill    (R2's proven grid-stride zero sweep)         ~66 us
//   K3 scatter ones + loss (unconditional, zeros all laid)  ~8 us
// Fused compute+store variants all plateau at ~4.2 TB/s write BW (R5-R10);
// store-only dispatches sustain ~6.8 TB/s. Serial split banks that.

#pragma clang fp contract(off)

#define KCB   512
#define SPB   110592          // 48^3
#define NPTS  221184
#define NBLK  864             // argmin blocks: 256 points each
#define FBLK  2048            // fill blocks
#define OUT_OFF 1
#define ENC_OFF 1769473LL     // 1 + 2*8*SPB ; %4 == 1
#define G4_BASE 442369LL      // (ENC_OFF + 3) / 4 : first aligned float4
#define G4_COUNT 28311551LL   // aligned float4 slots in enc region
#define TAIL_IDX 115015680LL  // ENC_OFF + 113246208 - 1

// K1: argmin + out + loss partials + u16 indices (no enc traffic).
__global__ __launch_bounds__(64) void argmin_kernel(const float* __restrict__ x,
                                                    const float* __restrict__ e,
                                                    float* __restrict__ dout,
                                                    unsigned short* __restrict__ idxout,
                                                    float* __restrict__ partials) {
    __shared__ float cb[KCB * 8];    // 16 KB codebook [512][8]
    __shared__ float sse[KCB];       // 2 KB row norms
    const int L   = threadIdx.x;     // 0..63, one wave per block
    const int blk = blockIdx.x;
    const int b   = (blk >= 432) ? 1 : 0;          // blocks don't straddle batch
    const int s0  = blk * 256 - b * SPB;           // row q*64+L -> spatial s0+q*64+L

    // x loads early: xv[q][c], coalesced 256B per (c,q)
    const float* xb = x + (size_t)b * (8 * SPB) + s0 + L;
    float xv[4][8];
    #pragma unroll
    for (int q = 0; q < 4; ++q)
        #pragma unroll
        for (int c = 0; c < 8; ++c)
            xv[q][c] = xb[(size_t)c * SPB + q * 64];

    // stage codebook (1024 float4, 16 per lane)
    {
        float4* cb4 = (float4*)cb;
        const float4* e4 = (const float4*)e;
        #pragma unroll
        for (int i = 0; i < 16; ++i) cb4[i * 64 + L] = e4[i * 64 + L];
    }
    __syncthreads();
    // row norms: numpy 8-elem pairwise tree (contract off: squares round first)
    #pragma unroll
    for (int j = 0; j < 8; ++j) {
        int r = j * 64 + L;
        const float* row = cb + (r << 3);
        sse[r] = ((row[0]*row[0] + row[1]*row[1]) + (row[2]*row[2] + row[3]*row[3]))
               + ((row[4]*row[4] + row[5]*row[5]) + (row[6]*row[6] + row[7]*row[7]));
    }
    __syncthreads();

    // sum(x^2), numpy tree, per point
    float sx[4];
    #pragma unroll
    for (int q = 0; q < 4; ++q)
        sx[q] = ((xv[q][0]*xv[q][0] + xv[q][1]*xv[q][1]) + (xv[q][2]*xv[q][2] + xv[q][3]*xv[q][3]))
              + ((xv[q][4]*xv[q][4] + xv[q][5]*xv[q][5]) + (xv[q][6]*xv[q][6] + xv[q][7]*xv[q][7]));

    float bestE[4], bestO[4];
    int   idxE[4], idxO[4];
    #pragma unroll
    for (int q = 0; q < 4; ++q) {
        bestE[q] = 3.402823466e38f; bestO[q] = 3.402823466e38f;
        idxE[q] = 0; idxO[q] = 1;
    }

    // argmin_k fl( fl(sx+se_k) - 2*dot_k ), first-min tie rule; dual chains.
    #pragma unroll 1
    for (int i = 0; i < 256; ++i) {
        const int k = i * 2;
        const float4* ek = (const float4*)(cb + (k << 3));  // rows k,k+1 (broadcast)
        float4 r0a = ek[0], r0b = ek[1], r1a = ek[2], r1b = ek[3];
        float2 s01 = *(const float2*)(sse + k);

        #pragma unroll
        for (int q = 0; q < 4; ++q) {
            float d0 =       xv[q][0] * r0a.x;
            d0 = __builtin_fmaf(xv[q][1], r0a.y, d0);
            d0 = __builtin_fmaf(xv[q][2], r0a.z, d0);
            d0 = __builtin_fmaf(xv[q][3], r0a.w, d0);
            d0 = __builtin_fmaf(xv[q][4], r0b.x, d0);
            d0 = __builtin_fmaf(xv[q][5], r0b.y, d0);
            d0 = __builtin_fmaf(xv[q][6], r0b.z, d0);
            d0 = __builtin_fmaf(xv[q][7], r0b.w, d0);
            float dist0 = __builtin_fmaf(-2.0f, d0, sx[q] + s01.x);

            float d1 =       xv[q][0] * r1a.x;
            d1 = __builtin_fmaf(xv[q][1], r1a.y, d1);
            d1 = __builtin_fmaf(xv[q][2], r1a.z, d1);
            d1 = __builtin_fmaf(xv[q][3], r1a.w, d1);
            d1 = __builtin_fmaf(xv[q][4], r1b.x, d1);
            d1 = __builtin_fmaf(xv[q][5], r1b.y, d1);
            d1 = __builtin_fmaf(xv[q][6], r1b.z, d1);
            d1 = __builtin_fmaf(xv[q][7], r1b.w, d1);
            float dist1 = __builtin_fmaf(-2.0f, d1, sx[q] + s01.y);

            bool l0 = dist0 < bestE[q];
            bestE[q] = l0 ? dist0 : bestE[q];
            idxE[q]  = l0 ? k     : idxE[q];
            bool l1 = dist1 < bestO[q];
            bestO[q] = l1 ? dist1 : bestO[q];
            idxO[q]  = l1 ? k + 1 : idxO[q];
        }
    }

    // merge chains (global first-min tie rule), record indices
    int bidx[4];
    #pragma unroll
    for (int q = 0; q < 4; ++q) {
        bool ow = (bestO[q] < bestE[q]) || ((bestO[q] == bestE[q]) && (idxO[q] < idxE[q]));
        bidx[q] = ow ? idxO[q] : idxE[q];
        idxout[blk * 256 + q * 64 + L] = (unsigned short)bidx[q];
    }

    // out region + loss partial
    float part = 0.0f;
    float* outp = dout + OUT_OFF + (size_t)b * (8 * SPB) + s0 + L;
    #pragma unroll
    for (int q = 0; q < 4; ++q) {
        const float4* qr4 = (const float4*)(cb + (bidx[q] << 3));
        float4 qa = qr4[0], qb = qr4[1];
        float qv[8] = {qa.x, qa.y, qa.z, qa.w, qb.x, qb.y, qb.z, qb.w};
        #pragma unroll
        for (int c = 0; c < 8; ++c) {
            float dq = qv[c] - xv[q][c];
            part += dq * dq;
            outp[(size_t)c * SPB + q * 64] = qv[c];
        }
    }

    // deterministic wave tree reduction
    #pragma unroll
    for (int off = 32; off > 0; off >>= 1)
        part += __shfl_down(part, off, 64);
    if (L == 0) partials[blk] = part;
}

// K2: pure streaming zero-fill of the enc region (proven ~6.5-6.8 TB/s).
__global__ __launch_bounds__(256) void fill_kernel(float* __restrict__ dout) {
    const long long g0 = (long long)blockIdx.x * 256 + threadIdx.x;
    float4* g4 = (float4*)dout + G4_BASE;
    const float4 z = make_float4(0.f, 0.f, 0.f, 0.f);
    #pragma unroll 1
    for (long long j = g0; j < G4_COUNT; j += (long long)FBLK * 256)
        g4[j] = z;
    if (g0 == 0) {
        dout[ENC_OFF]     = 0.f;
        dout[ENC_OFF + 1] = 0.f;
        dout[ENC_OFF + 2] = 0.f;
        dout[TAIL_IDX]    = 0.f;
    }
}

// K3: scatter the 221184 ones (all zeros already laid by K2 -> unconditional),
// and finalize the loss in block 0.
__global__ __launch_bounds__(256) void scatter_loss(const unsigned short* __restrict__ idx,
                                                    const float* __restrict__ partials,
                                                    float* __restrict__ dout) {
    const int t = threadIdx.x;
    const int n = blockIdx.x * 256 + t;             // < 221184 (864 blocks)
    const int k = idx[n];
    dout[ENC_OFF + (long long)n * KCB + k] = 1.0f;

    if (blockIdx.x == 0) {
        __shared__ float sl[256];
        float a = 0.0f;
        for (int j = t; j < NBLK; j += 256) a += partials[j];  // fixed order
        sl[t] = a;
        __syncthreads();
        for (int off = 128; off > 0; off >>= 1) {
            if (t < off) sl[t] += sl[t + off];
            __syncthreads();
        }
        if (t == 0) {
            float m = sl[0] / 1769472.0f;
            m = fminf(fmaxf(m, 0.0f), 10.0f);
            dout[0] = m + 0.25f * m;   // q_latent + beta*e_latent (equal values)
        }
    }
}

extern "C" void kernel_launch(void* const* d_in, const int* in_sizes, int n_in,
                              void* d_out, int out_size, void* d_ws, size_t ws_size,
                              hipStream_t stream) {
    const float* x = (const float*)d_in[0];
    const float* e = (const float*)d_in[1];
    float* dout = (float*)d_out;
    unsigned short* idx = (unsigned short*)d_ws;            // 221184 u16 = 432 KB
    float* partials     = (float*)((char*)d_ws + NPTS * sizeof(unsigned short));

    hipLaunchKernelGGL(argmin_kernel, dim3(NBLK), dim3(64),  0, stream, x, e, dout, idx, partials);
    hipLaunchKernelGGL(fill_kernel,   dim3(FBLK), dim3(256), 0, stream, dout);
    hipLaunchKernelGGL(scatter_loss,  dim3(NBLK), dim3(256), 0, stream, idx, partials, dout);
}

// Round 12
// 132.644 us; speedup vs baseline: 1.4319x; 1.4319x over previous
//
#include <hip/hip_runtime.h>

// VectorQuantizer: x [2,8,48,48,48] f32, embed [512,8] f32
// d_out: loss (1) | out (1769472) | encodings (221184*512 = 113246208)
// R12: R4's argmin geometry (864 x 256thr, 1 pt/thread, 13.5 waves/CU --
// fastest measured argmin, ~74us, LDS-broadcast-throughput-bound) with the
// 453MB zero-stream spread EVENLY through the k-loop (half-wave float4
// store per iter -> 6.75KB/CU/round < drain rate -> fully hidden).
// Epilogue after __syncthreads(): edges, ones, out, loss partials.

#pragma clang fp contract(off)

#define KCB   512
#define SPB   110592          // 48^3
#define NBLK  864             // 256 points per block
#define OUT_OFF 1
#define ENC_OFF 1769473LL     // 1 + 2*8*SPB ; %4 == 1
#define G4_BASE 442369LL      // (ENC_OFF + 3) / 4

__global__ __launch_bounds__(256) void vq_main(const float* __restrict__ x,
                                               const float* __restrict__ e,
                                               float* __restrict__ dout,
                                               float* __restrict__ partials) {
    __shared__ float cb[KCB * 8];    // 16 KB codebook [512][8]
    __shared__ float sse[KCB];       // 2 KB row norms
    __shared__ float sred[256];
    const int t   = threadIdx.x;
    const int blk = blockIdx.x;
    const int b   = (blk >= 432) ? 1 : 0;          // blocks don't straddle batch
    const int s   = blk * 256 - b * SPB + t;       // this thread's spatial index

    // x loads early (coalesced per channel)
    const float* xb = x + (size_t)b * (8 * SPB) + s;
    float xv[8];
    #pragma unroll
    for (int c = 0; c < 8; ++c) xv[c] = xb[(size_t)c * SPB];

    // stage codebook (1024 float4, 4 per thread)
    {
        float4* cb4 = (float4*)cb;
        const float4* e4 = (const float4*)e;
        #pragma unroll
        for (int i = 0; i < 4; ++i) cb4[i * 256 + t] = e4[i * 256 + t];
    }
    __syncthreads();
    // row norms: numpy 8-elem pairwise tree (contract off: squares round first)
    #pragma unroll
    for (int j = 0; j < 2; ++j) {
        int r = j * 256 + t;
        const float* row = cb + (r << 3);
        sse[r] = ((row[0]*row[0] + row[1]*row[1]) + (row[2]*row[2] + row[3]*row[3]))
               + ((row[4]*row[4] + row[5]*row[5]) + (row[6]*row[6] + row[7]*row[7]));
    }
    __syncthreads();

    // sum(x^2), numpy tree
    float sx = ((xv[0]*xv[0] + xv[1]*xv[1]) + (xv[2]*xv[2] + xv[3]*xv[3]))
             + ((xv[4]*xv[4] + xv[5]*xv[5]) + (xv[6]*xv[6] + xv[7]*xv[7]));

    float bestE = 3.402823466e38f, bestO = 3.402823466e38f;
    int   idxE = 0, idxO = 1;

    // fused zero-stream: block region = 131072 floats at ENC_OFF+blk*131072
    // (%4==1): 3 head floats, 32767 aligned float4 slots, 1 tail float.
    // iter i: threads with (t&1)==(i&1) store slot i*128 + (t>>1)
    // -> 128 slots/iter, 32768 total, skip slot 32767 (boundary-spanning).
    float4* encb = (float4*)dout + (G4_BASE + (long long)blk * 32768);
    float*  encf = dout + (ENC_OFF + (long long)blk * 131072);
    const float4 z4 = make_float4(0.f, 0.f, 0.f, 0.f);

    // argmin_k fl( fl(sx+se_k) - 2*dot_k ), first-min tie rule; dual chains.
    #pragma unroll 2
    for (int i = 0; i < 256; ++i) {
        const int k = i * 2;
        const float4* ek = (const float4*)(cb + (k << 3));  // rows k,k+1 (broadcast)
        float4 r0a = ek[0], r0b = ek[1], r1a = ek[2], r1b = ek[3];
        float2 s01 = *(const float2*)(sse + k);

        // evenly-spread zero store (half-wave per iter, hidden under LDS pace)
        if (((t ^ i) & 1) == 0) {
            int slot = i * 128 + (t >> 1);
            if (slot != 32767)
                encb[slot] = z4;
        }

        float d0 =       xv[0] * r0a.x;
        d0 = __builtin_fmaf(xv[1], r0a.y, d0);
        d0 = __builtin_fmaf(xv[2], r0a.z, d0);
        d0 = __builtin_fmaf(xv[3], r0a.w, d0);
        d0 = __builtin_fmaf(xv[4], r0b.x, d0);
        d0 = __builtin_fmaf(xv[5], r0b.y, d0);
        d0 = __builtin_fmaf(xv[6], r0b.z, d0);
        d0 = __builtin_fmaf(xv[7], r0b.w, d0);
        float dist0 = __builtin_fmaf(-2.0f, d0, sx + s01.x);

        float d1 =       xv[0] * r1a.x;
        d1 = __builtin_fmaf(xv[1], r1a.y, d1);
        d1 = __builtin_fmaf(xv[2], r1a.z, d1);
        d1 = __builtin_fmaf(xv[3], r1a.w, d1);
        d1 = __builtin_fmaf(xv[4], r1b.x, d1);
        d1 = __builtin_fmaf(xv[5], r1b.y, d1);
        d1 = __builtin_fmaf(xv[6], r1b.z, d1);
        d1 = __builtin_fmaf(xv[7], r1b.w, d1);
        float dist1 = __builtin_fmaf(-2.0f, d1, sx + s01.y);

        bool l0 = dist0 < bestE;
        bestE = l0 ? dist0 : bestE;
        idxE  = l0 ? k     : idxE;
        bool l1 = dist1 < bestO;
        bestO = l1 ? dist1 : bestO;
        idxO  = l1 ? k + 1 : idxO;
    }

    // merge chains (global first-min tie rule)
    bool ow = (bestO < bestE) || ((bestO == bestE) && (idxO < idxE));
    const int bidx = ow ? idxO : idxE;

    // barrier: every wave drains its own vmcnt before s_barrier -> all zeros
    // of this block's region are complete (same CU -> same L2) past here.
    __syncthreads();

    // head / tail scalars of this block's region
    if (t < 3)       encf[t]      = 0.f;
    else if (t == 3) encf[131071] = 0.f;

    // the one for this thread's row (row t of the block)
    encf[(size_t)t * 512 + bidx] = 1.0f;

    // out region + loss partial
    const float4* qr4 = (const float4*)(cb + (bidx << 3));
    float4 qa = qr4[0], qb = qr4[1];
    float qv[8] = {qa.x, qa.y, qa.z, qa.w, qb.x, qb.y, qb.z, qb.w};
    float part = 0.0f;
    float* outp = dout + OUT_OFF + (size_t)b * (8 * SPB) + s;
    #pragma unroll
    for (int c = 0; c < 8; ++c) {
        float dq = qv[c] - xv[c];
        part += dq * dq;
        outp[(size_t)c * SPB] = qv[c];
    }

    // deterministic block reduction
    sred[t] = part;
    __syncthreads();
    for (int off = 128; off > 0; off >>= 1) {
        if (t < off) sred[t] += sred[t + off];
        __syncthreads();
    }
    if (t == 0) partials[blk] = sred[0];
}

__global__ __launch_bounds__(256) void loss_kernel(const float* __restrict__ partials,
                                                   float* __restrict__ dout) {
    __shared__ float sred[256];
    int t = threadIdx.x;
    float a = 0.0f;
    for (int j = t; j < NBLK; j += 256) a += partials[j];  // fixed order
    sred[t] = a;
    __syncthreads();
    for (int off = 128; off > 0; off >>= 1) {
        if (t < off) sred[t] += sred[t + off];
        __syncthreads();
    }
    if (t == 0) {
        float m = sred[0] / 1769472.0f;
        m = fminf(fmaxf(m, 0.0f), 10.0f);
        dout[0] = m + 0.25f * m;   // q_latent + beta*e_latent (equal values)
    }
}

extern "C" void kernel_launch(void* const* d_in, const int* in_sizes, int n_in,
                              void* d_out, int out_size, void* d_ws, size_t ws_size,
                              hipStream_t stream) {
    const float* x = (const float*)d_in[0];
    const float* e = (const float*)d_in[1];
    float* dout     = (float*)d_out;
    float* partials = (float*)d_ws;     // 864 floats

    hipLaunchKernelGGL(vq_main,     dim3(NBLK), dim3(256), 0, stream, x, e, dout, partials);
    hipLaunchKernelGGL(loss_kernel, dim3(1),    dim3(256), 0, stream, partials, dout);
}